// Round 16
// baseline (170.941 us; speedup 1.0000x reference)
//
#include <hip/hip_runtime.h>
#include <math.h>

#define E   1024
#define H   16
#define DH  64
#define CD  512
#define S   2048
#define B   16
#define SRC (S + 1)      // 2049
#define SPAD 2052        // padded score row stride
#define SCALE 0.125f     // DH^-0.5

// ws layout (float offsets) — GP now 16 slabs; downstream shifted
#define OFF_CTXP 0                 // [B][E]
#define OFF_Q0   16384             // [B][E]
#define OFF_BKP  32768             // [E]
#define OFF_Q1S  33792             // [B][E]
#define OFF_TT   66560             // t [bh=256][f=1024]
#define OFF_GP   328960            // g_part [16][bh][E]; after k_gsum, [0] = final g
#define OFF_SC   4523264           // scores [bh][SPAD]
#define OFF_WT   5048576           // w [b][h][SRC]
#define OFF_UP   5573120           // u_part [16][b][h][E]
#define OFF_U    9767424           // u [b][h][E]
#define OFF_AP   10029568          // attn_pre [b][E]

// ---- stage 1: ctxp, q0, bkp (16-lane-group GEMV, per-b blocks) ------------
__global__ __launch_bounds__(256) void k_pre1(
    const float* __restrict__ query, const float* __restrict__ context,
    const float* __restrict__ ipw, const float* __restrict__ ipb,
    const float* __restrict__ cw, const float* __restrict__ cb,
    float* __restrict__ ws)
{
    int b  = blockIdx.x >> 6;
    int et = blockIdx.x & 63;
    int grp = threadIdx.x >> 4, l = threadIdx.x & 15;
    int e = et * 16 + grp;
    const float* crow = cw + (size_t)e * (CD + E);
    const float* ctx  = context + b * CD;
    float a1 = 0.f;
    #pragma unroll
    for (int c = l * 4; c < CD; c += 64) {
        float4 w4 = *(const float4*)(crow + c);
        float4 x4 = *(const float4*)(ctx + c);
        a1 += w4.x*x4.x + w4.y*x4.y + w4.z*x4.z + w4.w*x4.w;
    }
    const float* qrow = query + b * E;
    const float* wrow = ipw + (size_t)e * E;   // Wq row e
    float a2 = 0.f;
    #pragma unroll
    for (int f = l * 4; f < E; f += 64) {
        float4 w4 = *(const float4*)(wrow + f);
        float4 x4 = *(const float4*)(qrow + f);
        a2 += w4.x*x4.x + w4.y*x4.y + w4.z*x4.z + w4.w*x4.w;
    }
    float a3 = 0.f;
    if (b == 0) {   // bkp[e] = Wc2[e,:]·ipb[E:2E]
        const float* c2 = crow + CD;
        const float* bk = ipb + E;
        #pragma unroll
        for (int f = l * 4; f < E; f += 64) {
            float4 w4 = *(const float4*)(c2 + f);
            float4 x4 = *(const float4*)(bk + f);
            a3 += w4.x*x4.x + w4.y*x4.y + w4.z*x4.z + w4.w*x4.w;
        }
    }
    #pragma unroll
    for (int m = 8; m >= 1; m >>= 1) {
        a1 += __shfl_xor(a1, m, 64);
        a2 += __shfl_xor(a2, m, 64);
        a3 += __shfl_xor(a3, m, 64);
    }
    if (l == 0) {
        ws[OFF_CTXP + b*E + e] = a1 + cb[e];
        ws[OFF_Q0   + b*E + e] = a2 + ipb[e];
        if (b == 0) ws[OFF_BKP + e] = a3;
    }
}

// ---- fused stage 2+3: q1s (scaled) then t[bh][f], block = (b,h) -----------
__global__ __launch_bounds__(1024) void k_pre23(
    const float* __restrict__ cw, float* __restrict__ ws)
{
    int b = blockIdx.x >> 4;
    int h = blockIdx.x & 15;
    {
        int grp = threadIdx.x >> 4, l = threadIdx.x & 15;   // grp 0..63
        int e = h*64 + grp;
        const float* q0 = ws + OFF_Q0 + b*E;
        const float* c2row = cw + (size_t)e * (CD + E) + CD;  // Wc2 row e
        float acc = 0.f;
        #pragma unroll
        for (int f = l * 4; f < E; f += 64) {
            float4 w4 = *(const float4*)(c2row + f);
            float4 x4 = *(const float4*)(q0 + f);
            acc += w4.x*x4.x + w4.y*x4.y + w4.z*x4.z + w4.w*x4.w;
        }
        #pragma unroll
        for (int m = 8; m >= 1; m >>= 1) acc += __shfl_xor(acc, m, 64);
        if (l == 0) {
            float ctxp = ws[OFF_CTXP + b*E + e];
            ws[OFF_Q1S + b*E + e] = (ctxp + acc) * SCALE;
        }
    }
    __syncthreads();
    {
        int f = threadIdx.x;
        const float* q1 = ws + OFF_Q1S + b*E + h*DH;
        float a = 0.f;
        #pragma unroll 8
        for (int d = 0; d < DH; ++d) {
            float q = q1[d];                                  // uniform -> s_load
            a += q * cw[(size_t)(h*DH + d)*(CD+E) + CD + f];  // contiguous 4KB/d
        }
        ws[OFF_TT + (size_t)(b*16 + h)*1024 + f] = a;
    }
}

// ---- g_part[kc][bh][e]: kc=16 f-chunks of 64, mt=8 blocks of 32 bh --------
// Wk re-read 8x (32 MB); GP 16 slabs (32 MB RW). grid 512 = 2 blocks/CU.
__global__ __launch_bounds__(256) void k_g(
    const float* __restrict__ ipw, float* __restrict__ ws)
{
    int kc = blockIdx.x >> 5;            // 0..15 (f chunk of 64)
    int nt = (blockIdx.x >> 3) & 3;      // 0..3  (n tile of 256)
    int mt = blockIdx.x & 7;             // 0..7  (m tile of 32 bh)
    int n  = (nt << 8) + threadIdx.x;
    int m0 = mt << 5;
    int f0 = kc << 6;
    const float* tT = ws + OFF_TT;       // [bh][1024]
    const float* wk = ipw + (size_t)E * E;   // Wk rows
    float acc[32];
    #pragma unroll
    for (int m = 0; m < 32; ++m) acc[m] = 0.f;
    #pragma unroll 2
    for (int f = f0; f < f0 + 64; ++f) {
        float wv = wk[(size_t)f*E + n];
        #pragma unroll
        for (int m = 0; m < 32; ++m)
            acc[m] += tT[(size_t)(m0+m)*1024 + f] * wv;   // uniform -> s_load
    }
    float* gp = ws + OFF_GP + (size_t)kc * (256*E);
    #pragma unroll
    for (int m = 0; m < 32; ++m) gp[(size_t)(m0+m)*E + n] = acc[m];
}

// ---- sum 16 g partials into slab 0 (float4) ----------
__global__ __launch_bounds__(256) void k_gsum(float* __restrict__ ws)
{
    int id = blockIdx.x * 256 + threadIdx.x;   // 65536 threads, float4 each
    float4 a; a.x = a.y = a.z = a.w = 0.f;
    #pragma unroll
    for (int c = 0; c < 16; ++c) {
        float4 v = *(const float4*)(ws + OFF_GP + (size_t)c*(256*E) + id*4);
        a.x += v.x; a.y += v.y; a.z += v.z; a.w += v.w;
    }
    *(float4*)(ws + OFF_GP + id*4) = a;
}

// ---- scores[bh][s] = key·g + c0 (scalar-g GEMV; R6 core) ----------
__global__ __launch_bounds__(512, 2) void k_scores(
    const float* __restrict__ key, const float* __restrict__ bias_k,
    float* __restrict__ ws)
{
    __shared__ float lds[8704];    // [8][64][17]
    __shared__ float exA[256];     // c0 partials [h][seg]
    __shared__ float exB[256];     // sS partials [h][seg]
    int b  = blockIdx.x >> 5;
    int sc = blockIdx.x & 31;      // s-chunk of 64 rows
    int tid = threadIdx.x;

    if (tid < 256) {               // c0 = q1·(ctxp+bkp), sS = q1·bias_k
        int h = tid >> 4, seg = tid & 15;
        const float* q1 = ws + OFF_Q1S + b*E + h*DH + seg*4;
        const float* cp = ws + OFF_CTXP + b*E + h*DH + seg*4;
        const float* bp = ws + OFF_BKP + h*DH + seg*4;
        const float* bk = bias_k + h*DH + seg*4;
        float4 q4 = *(const float4*)q1;
        float4 c4 = *(const float4*)cp;
        float4 p4 = *(const float4*)bp;
        float4 b4 = *(const float4*)bk;
        exA[tid] = q4.x*(c4.x+p4.x) + q4.y*(c4.y+p4.y)
                 + q4.z*(c4.z+p4.z) + q4.w*(c4.w+p4.w);
        exB[tid] = q4.x*b4.x + q4.y*b4.y + q4.z*b4.z + q4.w*b4.w;
    }

    int w = __builtin_amdgcn_readfirstlane(tid >> 6);   // wave id 0..7
    int l = tid & 63;
    int r = sc*64 + l;
    const float* kbase = key + (((size_t)r*B + b) << 10) + w*128;
    const float* gbase = ws + OFF_GP + (size_t)b*(16*1024) + w*128;  // uniform
    float acc[16];
    #pragma unroll
    for (int h = 0; h < 16; ++h) acc[h] = 0.f;

    #pragma unroll 1
    for (int sub = 0; sub < 4; ++sub) {
        const float* kp = kbase + sub*32;
        float4 kk[8];
        #pragma unroll
        for (int j = 0; j < 8; ++j) kk[j] = *(const float4*)(kp + j*4);
        const float* gp0 = gbase + sub*32;
        #pragma unroll
        for (int h = 0; h < 16; ++h) {
            const float* gp = gp0 + h*1024;      // uniform -> s_load
            float a = 0.f;
            #pragma unroll
            for (int j = 0; j < 8; ++j) {
                float4 gv = *(const float4*)(gp + j*4);
                a += kk[j].x*gv.x + kk[j].y*gv.y + kk[j].z*gv.z + kk[j].w*gv.w;
            }
            acc[h] += a;
        }
    }

    float* pr = lds + (w*64 + l)*17;
    #pragma unroll
    for (int h = 0; h < 16; ++h) pr[h] = acc[h];
    __syncthreads();

    int l2 = tid & 63, pp = tid >> 6;
    #pragma unroll
    for (int k2 = 0; k2 < 2; ++k2) {
        int h = pp*2 + k2;
        float sum = 0.f;
        #pragma unroll
        for (int ww = 0; ww < 8; ++ww) sum += lds[(ww*64 + l2)*17 + h];
        float c0 = 0.f;
        #pragma unroll
        for (int seg = 0; seg < 16; ++seg) c0 += exA[h*16 + seg];
        int bh = b*16 + h;
        ws[OFF_SC + (size_t)bh*SPAD + sc*64 + l2] = sum + c0;
        if (sc == 0 && l2 == 0) {
            float sb = 0.f;
            #pragma unroll
            for (int seg = 0; seg < 16; ++seg) sb += exB[h*16 + seg];
            ws[OFF_SC + (size_t)bh*SPAD + S] = sb;
        }
    }
}

// ---- softmax per (b,h) row; write w[b][h][s] ----------
__global__ __launch_bounds__(256) void k_softmax(float* __restrict__ ws)
{
    int bh = blockIdx.x;
    int tid = threadIdx.x, lane = tid & 63, wid = tid >> 6;
    const float* row = ws + OFF_SC + (size_t)bh*SPAD;
    __shared__ float red[4];
    float v[9];
    float m = -1e30f;
    #pragma unroll
    for (int i = 0; i < 9; ++i) {
        int s = tid + (i << 8);
        if (s < SRC) { v[i] = row[s]; m = fmaxf(m, v[i]); } else v[i] = -1e30f;
    }
    #pragma unroll
    for (int k = 1; k < 64; k <<= 1) m = fmaxf(m, __shfl_xor(m, k, 64));
    if (lane == 0) red[wid] = m;
    __syncthreads();
    m = fmaxf(fmaxf(red[0], red[1]), fmaxf(red[2], red[3]));
    __syncthreads();
    float sum = 0.f;
    #pragma unroll
    for (int i = 0; i < 9; ++i) {
        int s = tid + (i << 8);
        if (s < SRC) { v[i] = expf(v[i] - m); sum += v[i]; }
    }
    #pragma unroll
    for (int k = 1; k < 64; k <<= 1) sum += __shfl_xor(sum, k, 64);
    if (lane == 0) red[wid] = sum;
    __syncthreads();
    sum = red[0] + red[1] + red[2] + red[3];
    float inv = 1.0f / sum;
    float* wrow = ws + OFF_WT + (size_t)bh*SRC;
    #pragma unroll
    for (int i = 0; i < 9; ++i) {
        int s = tid + (i << 8);
        if (s < SRC) wrow[s] = v[i] * inv;
    }
}

// ---- u_part[sc][b][h][f] = Σ_s w·value : 16 slabs of 128 s, f-half split --
__global__ __launch_bounds__(256) void k_u(
    const float* __restrict__ value, float* __restrict__ ws)
{
    int b  = blockIdx.x >> 5;
    int sc = (blockIdx.x >> 1) & 15;     // 16 s-chunks of 128
    int fh = blockIdx.x & 1;             // f half
    int f  = (fh << 9) + threadIdx.x * 2;
    const float* wtb = ws + OFF_WT + (size_t)(b*16)*SRC;
    float2 acc[16];
    #pragma unroll
    for (int h = 0; h < 16; ++h) { acc[h].x = 0.f; acc[h].y = 0.f; }
    int s0 = sc * 128;
    #pragma unroll 1
    for (int sub = 0; sub < 16; ++sub) {
        int ss = s0 + sub*8;
        float2 vv[8];
        #pragma unroll
        for (int j = 0; j < 8; ++j)
            vv[j] = *(const float2*)(value + (((size_t)(ss+j)*B + b) << 10) + f);
        #pragma unroll
        for (int h = 0; h < 16; ++h) {
            const float* wr = wtb + (size_t)h*SRC + ss;   // uniform -> s_load
            #pragma unroll
            for (int j = 0; j < 8; ++j) {
                float wv = wr[j];
                acc[h].x += wv*vv[j].x; acc[h].y += wv*vv[j].y;
            }
        }
    }
    float* up = ws + OFF_UP + ((size_t)(sc*B + b)*16)*1024;
    #pragma unroll
    for (int h = 0; h < 16; ++h)
        *(float2*)(up + (size_t)h*1024 + f) = acc[h];
}

// ---- reduce 16 u_part slabs (float4) + fused avg_weights output -----------
__global__ __launch_bounds__(256) void k_ured(
    float* __restrict__ ws, float* __restrict__ out)
{
    int id = blockIdx.x * 256 + threadIdx.x;   // 65536 threads, float4 each
    float4 a; a.x = a.y = a.z = a.w = 0.f;
    #pragma unroll
    for (int c = 0; c < 16; ++c) {
        float4 v = *(const float4*)(ws + OFF_UP + (size_t)c*(B*H*E) + id*4);
        a.x += v.x; a.y += v.y; a.z += v.z; a.w += v.w;
    }
    *(float4*)(ws + OFF_U + id*4) = a;

    // fused avg_weights: 32784 outputs, id < B*SRC
    if (id < B * SRC) {
        int b = id / SRC, s = id - b * SRC;
        const float* p = ws + OFF_WT + (size_t)(b*16)*SRC + s;
        float av = 0.f;
        #pragma unroll
        for (int h = 0; h < 16; ++h) av += p[(size_t)h*SRC];
        out[B*E + id] = av * (1.0f / H);
    }
}

// ---- attn_pre[b][e] (16-lane-group GEMV over u) ----------
__global__ __launch_bounds__(256) void k_attnpre(
    const float* __restrict__ ipw, const float* __restrict__ ipb,
    const float* __restrict__ bias_v, float* __restrict__ ws)
{
    int b  = blockIdx.x >> 6;
    int et = blockIdx.x & 63;
    int grp = threadIdx.x >> 4, l = threadIdx.x & 15;
    int e = et * 16 + grp;
    int h = e >> 6;
    const float* wvr = ipw + (size_t)(2*E + e) * E;   // Wv row e
    const float* ur  = ws + OFF_U + (size_t)(b*16 + h) * E;
    float acc = 0.f;
    #pragma unroll
    for (int ff = l * 4; ff < E; ff += 64) {
        float4 w4 = *(const float4*)(wvr + ff);
        float4 u4 = *(const float4*)(ur + ff);
        acc += w4.x*u4.x + w4.y*u4.y + w4.z*u4.z + w4.w*u4.w;
    }
    #pragma unroll
    for (int m = 8; m >= 1; m >>= 1) acc += __shfl_xor(acc, m, 64);
    if (l == 0) {
        float wS = ws[OFF_WT + (size_t)(b*16 + h)*SRC + S];
        ws[OFF_AP + b*E + e] = acc + ipb[2*E + e] * (1.0f - wS) + wS * bias_v[e];
    }
}

// ---- out projection (16-lane-group GEMV) ----------
__global__ __launch_bounds__(256) void k_out(
    const float* __restrict__ ow, const float* __restrict__ ob,
    const float* __restrict__ ws, float* __restrict__ out)
{
    int b  = blockIdx.x >> 6;
    int et = blockIdx.x & 63;
    int grp = threadIdx.x >> 4, l = threadIdx.x & 15;
    int o = et * 16 + grp;
    const float* wr = ow + (size_t)o * E;
    const float* ap = ws + OFF_AP + b*E;
    float acc = 0.f;
    #pragma unroll
    for (int e = l * 4; e < E; e += 64) {
        float4 w4 = *(const float4*)(wr + e);
        float4 a4 = *(const float4*)(ap + e);
        acc += w4.x*a4.x + w4.y*a4.y + w4.z*a4.z + w4.w*a4.w;
    }
    #pragma unroll
    for (int m = 8; m >= 1; m >>= 1) acc += __shfl_xor(acc, m, 64);
    if (l == 0) out[b*E + o] = acc + ob[o];
}

extern "C" void kernel_launch(void* const* d_in, const int* in_sizes, int n_in,
                              void* d_out, int out_size, void* d_ws, size_t ws_size,
                              hipStream_t stream)
{
    const float* query   = (const float*)d_in[0];
    const float* key     = (const float*)d_in[1];
    const float* value   = (const float*)d_in[2];
    const float* context = (const float*)d_in[3];
    const float* ipw     = (const float*)d_in[4];
    const float* ipb     = (const float*)d_in[5];
    const float* cw      = (const float*)d_in[6];
    const float* cb      = (const float*)d_in[7];
    const float* ow      = (const float*)d_in[8];
    const float* ob      = (const float*)d_in[9];
    const float* bias_k  = (const float*)d_in[10];
    const float* bias_v  = (const float*)d_in[11];
    float* out = (float*)d_out;
    float* ws  = (float*)d_ws;

    hipLaunchKernelGGL(k_pre1,    dim3(1024), dim3(256),  0, stream, query, context, ipw, ipb, cw, cb, ws);
    hipLaunchKernelGGL(k_pre23,   dim3(256),  dim3(1024), 0, stream, cw, ws);
    hipLaunchKernelGGL(k_g,       dim3(512),  dim3(256),  0, stream, ipw, ws);
    hipLaunchKernelGGL(k_gsum,    dim3(256),  dim3(256),  0, stream, ws);
    hipLaunchKernelGGL(k_scores,  dim3(512),  dim3(512),  0, stream, key, bias_k, ws);
    hipLaunchKernelGGL(k_softmax, dim3(256),  dim3(256),  0, stream, ws);
    hipLaunchKernelGGL(k_u,       dim3(512),  dim3(256),  0, stream, value, ws);
    hipLaunchKernelGGL(k_ured,    dim3(256),  dim3(256),  0, stream, ws, out);
    hipLaunchKernelGGL(k_attnpre, dim3(1024), dim3(256),  0, stream, ipw, ipb, bias_v, ws);
    hipLaunchKernelGGL(k_out,     dim3(1024), dim3(256),  0, stream, ow, ob, ws, out);
}

// Round 17
// 168.355 us; speedup vs baseline: 1.0154x; 1.0154x over previous
//
#include <hip/hip_runtime.h>
#include <math.h>

#define E   1024
#define H   16
#define DH  64
#define CD  512
#define S   2048
#define B   16
#define SRC (S + 1)      // 2049
#define SPAD 2052        // padded score row stride
#define SCALE 0.125f     // DH^-0.5

// ws layout (float offsets) — identical to R14/R15
#define OFF_CTXP 0                 // [B][E]
#define OFF_Q0   16384             // [B][E]
#define OFF_BKP  32768             // [E]
#define OFF_Q1S  33792             // [B][E]
#define OFF_TT   66560             // t [bh=256][f=1024]
#define OFF_GP   328960            // g_part [8][bh][E]; after k_gsum, [0] = final g
#define OFF_SC   2426112           // scores [bh][SPAD]
#define OFF_WT   2951424           // w [b][h][SRC]
#define OFF_UP   3475968           // u_part [16][b][h][E]
#define OFF_U    7670272           // u [b][h][E]
#define OFF_AP   7932416           // attn_pre [b][E]

// ---- stage 1: ctxp, q0, bkp (16-lane-group GEMV, per-b blocks) ------------
__global__ __launch_bounds__(256) void k_pre1(
    const float* __restrict__ query, const float* __restrict__ context,
    const float* __restrict__ ipw, const float* __restrict__ ipb,
    const float* __restrict__ cw, const float* __restrict__ cb,
    float* __restrict__ ws)
{
    int b  = blockIdx.x >> 6;
    int et = blockIdx.x & 63;
    int grp = threadIdx.x >> 4, l = threadIdx.x & 15;
    int e = et * 16 + grp;
    const float* crow = cw + (size_t)e * (CD + E);
    const float* ctx  = context + b * CD;
    float a1 = 0.f;
    #pragma unroll
    for (int c = l * 4; c < CD; c += 64) {
        float4 w4 = *(const float4*)(crow + c);
        float4 x4 = *(const float4*)(ctx + c);
        a1 += w4.x*x4.x + w4.y*x4.y + w4.z*x4.z + w4.w*x4.w;
    }
    const float* qrow = query + b * E;
    const float* wrow = ipw + (size_t)e * E;   // Wq row e
    float a2 = 0.f;
    #pragma unroll
    for (int f = l * 4; f < E; f += 64) {
        float4 w4 = *(const float4*)(wrow + f);
        float4 x4 = *(const float4*)(qrow + f);
        a2 += w4.x*x4.x + w4.y*x4.y + w4.z*x4.z + w4.w*x4.w;
    }
    float a3 = 0.f;
    if (b == 0) {   // bkp[e] = Wc2[e,:]·ipb[E:2E]
        const float* c2 = crow + CD;
        const float* bk = ipb + E;
        #pragma unroll
        for (int f = l * 4; f < E; f += 64) {
            float4 w4 = *(const float4*)(c2 + f);
            float4 x4 = *(const float4*)(bk + f);
            a3 += w4.x*x4.x + w4.y*x4.y + w4.z*x4.z + w4.w*x4.w;
        }
    }
    #pragma unroll
    for (int m = 8; m >= 1; m >>= 1) {
        a1 += __shfl_xor(a1, m, 64);
        a2 += __shfl_xor(a2, m, 64);
        a3 += __shfl_xor(a3, m, 64);
    }
    if (l == 0) {
        ws[OFF_CTXP + b*E + e] = a1 + cb[e];
        ws[OFF_Q0   + b*E + e] = a2 + ipb[e];
        if (b == 0) ws[OFF_BKP + e] = a3;
    }
}

// ---- fused stage 2+3: q1s (scaled) then t[bh][f], block = (b,h) -----------
// Phase 1: 64 groups x 16 lanes compute q1s[b, h*64 .. h*64+64).
// Phase 2 (after __syncthreads): t[bh][f] = sum_d q1s[b,h*64+d]*Wc2[h*64+d, f].
__global__ __launch_bounds__(1024) void k_pre23(
    const float* __restrict__ cw, float* __restrict__ ws)
{
    int b = blockIdx.x >> 4;
    int h = blockIdx.x & 15;
    {
        int grp = threadIdx.x >> 4, l = threadIdx.x & 15;   // grp 0..63
        int e = h*64 + grp;
        const float* q0 = ws + OFF_Q0 + b*E;
        const float* c2row = cw + (size_t)e * (CD + E) + CD;  // Wc2 row e
        float acc = 0.f;
        #pragma unroll
        for (int f = l * 4; f < E; f += 64) {
            float4 w4 = *(const float4*)(c2row + f);
            float4 x4 = *(const float4*)(q0 + f);
            acc += w4.x*x4.x + w4.y*x4.y + w4.z*x4.z + w4.w*x4.w;
        }
        #pragma unroll
        for (int m = 8; m >= 1; m >>= 1) acc += __shfl_xor(acc, m, 64);
        if (l == 0) {
            float ctxp = ws[OFF_CTXP + b*E + e];
            ws[OFF_Q1S + b*E + e] = (ctxp + acc) * SCALE;
        }
    }
    __syncthreads();
    {
        int f = threadIdx.x;
        const float* q1 = ws + OFF_Q1S + b*E + h*DH;
        float a = 0.f;
        #pragma unroll 8
        for (int d = 0; d < DH; ++d) {
            float q = q1[d];                                  // uniform -> s_load
            a += q * cw[(size_t)(h*DH + d)*(CD+E) + CD + f];  // contiguous 4KB/d
        }
        ws[OFF_TT + (size_t)(b*16 + h)*1024 + f] = a;
    }
}

// ---- g_part[kc][bh][e]: kc=8 f-chunks of 128, mt=16 bh, acc[16] -----------
__global__ __launch_bounds__(256) void k_g(
    const float* __restrict__ ipw, float* __restrict__ ws)
{
    int kc = blockIdx.x >> 6;            // 0..7  (f chunk of 128)
    int nt = (blockIdx.x >> 4) & 3;      // 0..3  (n tile of 256)
    int mt = blockIdx.x & 15;            // 0..15 (m tile of 16 bh)
    int n  = (nt << 8) + threadIdx.x;
    int m0 = mt << 4;
    int f0 = kc << 7;
    const float* tT = ws + OFF_TT;       // [bh][1024]
    const float* wk = ipw + (size_t)E * E;   // Wk rows
    float acc[16];
    #pragma unroll
    for (int m = 0; m < 16; ++m) acc[m] = 0.f;
    #pragma unroll 4
    for (int f = f0; f < f0 + 128; ++f) {
        float wv = wk[(size_t)f*E + n];
        #pragma unroll
        for (int m = 0; m < 16; ++m)
            acc[m] += tT[(size_t)(m0+m)*1024 + f] * wv;   // uniform -> s_load
    }
    float* gp = ws + OFF_GP + (size_t)kc * (256*E);
    #pragma unroll
    for (int m = 0; m < 16; ++m) gp[(size_t)(m0+m)*E + n] = acc[m];
}

// ---- sum 8 g partials into slab 0 (float4) ----------
__global__ __launch_bounds__(256) void k_gsum(float* __restrict__ ws)
{
    int id = blockIdx.x * 256 + threadIdx.x;   // 65536 threads, float4 each
    float4 a; a.x = a.y = a.z = a.w = 0.f;
    #pragma unroll
    for (int c = 0; c < 8; ++c) {
        float4 v = *(const float4*)(ws + OFF_GP + (size_t)c*(256*E) + id*4);
        a.x += v.x; a.y += v.y; a.z += v.z; a.w += v.w;
    }
    *(float4*)(ws + OFF_GP + id*4) = a;
}

// ---- scores[bh][s] = key·g + c0 (scalar-g GEMV; R6 core) ----------
__global__ __launch_bounds__(512, 2) void k_scores(
    const float* __restrict__ key, const float* __restrict__ bias_k,
    float* __restrict__ ws)
{
    __shared__ float lds[8704];    // [8][64][17]
    __shared__ float exA[256];     // c0 partials [h][seg]
    __shared__ float exB[256];     // sS partials [h][seg]
    int b  = blockIdx.x >> 5;
    int sc = blockIdx.x & 31;      // s-chunk of 64 rows
    int tid = threadIdx.x;

    if (tid < 256) {               // c0 = q1·(ctxp+bkp), sS = q1·bias_k
        int h = tid >> 4, seg = tid & 15;
        const float* q1 = ws + OFF_Q1S + b*E + h*DH + seg*4;
        const float* cp = ws + OFF_CTXP + b*E + h*DH + seg*4;
        const float* bp = ws + OFF_BKP + h*DH + seg*4;
        const float* bk = bias_k + h*DH + seg*4;
        float4 q4 = *(const float4*)q1;
        float4 c4 = *(const float4*)cp;
        float4 p4 = *(const float4*)bp;
        float4 b4 = *(const float4*)bk;
        exA[tid] = q4.x*(c4.x+p4.x) + q4.y*(c4.y+p4.y)
                 + q4.z*(c4.z+p4.z) + q4.w*(c4.w+p4.w);
        exB[tid] = q4.x*b4.x + q4.y*b4.y + q4.z*b4.z + q4.w*b4.w;
    }

    int w = __builtin_amdgcn_readfirstlane(tid >> 6);   // wave id 0..7
    int l = tid & 63;
    int r = sc*64 + l;
    const float* kbase = key + (((size_t)r*B + b) << 10) + w*128;
    const float* gbase = ws + OFF_GP + (size_t)b*(16*1024) + w*128;  // uniform
    float acc[16];
    #pragma unroll
    for (int h = 0; h < 16; ++h) acc[h] = 0.f;

    #pragma unroll 1
    for (int sub = 0; sub < 4; ++sub) {
        const float* kp = kbase + sub*32;
        float4 kk[8];
        #pragma unroll
        for (int j = 0; j < 8; ++j) kk[j] = *(const float4*)(kp + j*4);
        const float* gp0 = gbase + sub*32;
        #pragma unroll
        for (int h = 0; h < 16; ++h) {
            const float* gp = gp0 + h*1024;      // uniform -> s_load
            float a = 0.f;
            #pragma unroll
            for (int j = 0; j < 8; ++j) {
                float4 gv = *(const float4*)(gp + j*4);
                a += kk[j].x*gv.x + kk[j].y*gv.y + kk[j].z*gv.z + kk[j].w*gv.w;
            }
            acc[h] += a;
        }
    }

    float* pr = lds + (w*64 + l)*17;
    #pragma unroll
    for (int h = 0; h < 16; ++h) pr[h] = acc[h];
    __syncthreads();

    int l2 = tid & 63, pp = tid >> 6;
    #pragma unroll
    for (int k2 = 0; k2 < 2; ++k2) {
        int h = pp*2 + k2;
        float sum = 0.f;
        #pragma unroll
        for (int ww = 0; ww < 8; ++ww) sum += lds[(ww*64 + l2)*17 + h];
        float c0 = 0.f;
        #pragma unroll
        for (int seg = 0; seg < 16; ++seg) c0 += exA[h*16 + seg];
        int bh = b*16 + h;
        ws[OFF_SC + (size_t)bh*SPAD + sc*64 + l2] = sum + c0;
        if (sc == 0 && l2 == 0) {
            float sb = 0.f;
            #pragma unroll
            for (int seg = 0; seg < 16; ++seg) sb += exB[h*16 + seg];
            ws[OFF_SC + (size_t)bh*SPAD + S] = sb;
        }
    }
}

// ---- softmax per (b,h) row; write w[b][h][s] ----------
__global__ __launch_bounds__(256) void k_softmax(float* __restrict__ ws)
{
    int bh = blockIdx.x;
    int tid = threadIdx.x, lane = tid & 63, wid = tid >> 6;
    const float* row = ws + OFF_SC + (size_t)bh*SPAD;
    __shared__ float red[4];
    float v[9];
    float m = -1e30f;
    #pragma unroll
    for (int i = 0; i < 9; ++i) {
        int s = tid + (i << 8);
        if (s < SRC) { v[i] = row[s]; m = fmaxf(m, v[i]); } else v[i] = -1e30f;
    }
    #pragma unroll
    for (int k = 1; k < 64; k <<= 1) m = fmaxf(m, __shfl_xor(m, k, 64));
    if (lane == 0) red[wid] = m;
    __syncthreads();
    m = fmaxf(fmaxf(red[0], red[1]), fmaxf(red[2], red[3]));
    __syncthreads();
    float sum = 0.f;
    #pragma unroll
    for (int i = 0; i < 9; ++i) {
        int s = tid + (i << 8);
        if (s < SRC) { v[i] = expf(v[i] - m); sum += v[i]; }
    }
    #pragma unroll
    for (int k = 1; k < 64; k <<= 1) sum += __shfl_xor(sum, k, 64);
    if (lane == 0) red[wid] = sum;
    __syncthreads();
    sum = red[0] + red[1] + red[2] + red[3];
    float inv = 1.0f / sum;
    float* wrow = ws + OFF_WT + (size_t)bh*SRC;
    #pragma unroll
    for (int i = 0; i < 9; ++i) {
        int s = tid + (i << 8);
        if (s < SRC) wrow[s] = v[i] * inv;
    }
}

// ---- u_part[sc][b][h][f] = Σ_s w·value : 16 slabs of 128 s, f-half split --
__global__ __launch_bounds__(256) void k_u(
    const float* __restrict__ value, float* __restrict__ ws)
{
    int b  = blockIdx.x >> 5;
    int sc = (blockIdx.x >> 1) & 15;     // 16 s-chunks of 128
    int fh = blockIdx.x & 1;             // f half
    int f  = (fh << 9) + threadIdx.x * 2;
    const float* wtb = ws + OFF_WT + (size_t)(b*16)*SRC;
    float2 acc[16];
    #pragma unroll
    for (int h = 0; h < 16; ++h) { acc[h].x = 0.f; acc[h].y = 0.f; }
    int s0 = sc * 128;
    #pragma unroll 1
    for (int sub = 0; sub < 16; ++sub) {
        int ss = s0 + sub*8;
        float2 vv[8];
        #pragma unroll
        for (int j = 0; j < 8; ++j)
            vv[j] = *(const float2*)(value + (((size_t)(ss+j)*B + b) << 10) + f);
        #pragma unroll
        for (int h = 0; h < 16; ++h) {
            const float* wr = wtb + (size_t)h*SRC + ss;   // uniform -> s_load
            #pragma unroll
            for (int j = 0; j < 8; ++j) {
                float wv = wr[j];
                acc[h].x += wv*vv[j].x; acc[h].y += wv*vv[j].y;
            }
        }
    }
    float* up = ws + OFF_UP + ((size_t)(sc*B + b)*16)*1024;
    #pragma unroll
    for (int h = 0; h < 16; ++h)
        *(float2*)(up + (size_t)h*1024 + f) = acc[h];
}

// ---- reduce 16 u_part slabs (float4) + fused avg_weights output -----------
__global__ __launch_bounds__(256) void k_ured(
    float* __restrict__ ws, float* __restrict__ out)
{
    int id = blockIdx.x * 256 + threadIdx.x;   // 65536 threads, float4 each
    float4 a; a.x = a.y = a.z = a.w = 0.f;
    #pragma unroll
    for (int c = 0; c < 16; ++c) {
        float4 v = *(const float4*)(ws + OFF_UP + (size_t)c*(B*H*E) + id*4);
        a.x += v.x; a.y += v.y; a.z += v.z; a.w += v.w;
    }
    *(float4*)(ws + OFF_U + id*4) = a;

    // fused avg_weights: 32784 outputs, id < B*SRC
    if (id < B * SRC) {
        int b = id / SRC, s = id - b * SRC;
        const float* p = ws + OFF_WT + (size_t)(b*16)*SRC + s;
        float av = 0.f;
        #pragma unroll
        for (int h = 0; h < 16; ++h) av += p[(size_t)h*SRC];
        out[B*E + id] = av * (1.0f / H);
    }
}

// ---- attn_pre[b][e] (16-lane-group GEMV over u) ----------
__global__ __launch_bounds__(256) void k_attnpre(
    const float* __restrict__ ipw, const float* __restrict__ ipb,
    const float* __restrict__ bias_v, float* __restrict__ ws)
{
    int b  = blockIdx.x >> 6;
    int et = blockIdx.x & 63;
    int grp = threadIdx.x >> 4, l = threadIdx.x & 15;
    int e = et * 16 + grp;
    int h = e >> 6;
    const float* wvr = ipw + (size_t)(2*E + e) * E;   // Wv row e
    const float* ur  = ws + OFF_U + (size_t)(b*16 + h) * E;
    float acc = 0.f;
    #pragma unroll
    for (int ff = l * 4; ff < E; ff += 64) {
        float4 w4 = *(const float4*)(wvr + ff);
        float4 u4 = *(const float4*)(ur + ff);
        acc += w4.x*u4.x + w4.y*u4.y + w4.z*u4.z + w4.w*u4.w;
    }
    #pragma unroll
    for (int m = 8; m >= 1; m >>= 1) acc += __shfl_xor(acc, m, 64);
    if (l == 0) {
        float wS = ws[OFF_WT + (size_t)(b*16 + h)*SRC + S];
        ws[OFF_AP + b*E + e] = acc + ipb[2*E + e] * (1.0f - wS) + wS * bias_v[e];
    }
}

// ---- out projection (16-lane-group GEMV) ----------
__global__ __launch_bounds__(256) void k_out(
    const float* __restrict__ ow, const float* __restrict__ ob,
    const float* __restrict__ ws, float* __restrict__ out)
{
    int b  = blockIdx.x >> 6;
    int et = blockIdx.x & 63;
    int grp = threadIdx.x >> 4, l = threadIdx.x & 15;
    int o = et * 16 + grp;
    const float* wr = ow + (size_t)o * E;
    const float* ap = ws + OFF_AP + b*E;
    float acc = 0.f;
    #pragma unroll
    for (int e = l * 4; e < E; e += 64) {
        float4 w4 = *(const float4*)(wr + e);
        float4 a4 = *(const float4*)(ap + e);
        acc += w4.x*a4.x + w4.y*a4.y + w4.z*a4.z + w4.w*a4.w;
    }
    #pragma unroll
    for (int m = 8; m >= 1; m >>= 1) acc += __shfl_xor(acc, m, 64);
    if (l == 0) out[b*E + o] = acc + ob[o];
}

extern "C" void kernel_launch(void* const* d_in, const int* in_sizes, int n_in,
                              void* d_out, int out_size, void* d_ws, size_t ws_size,
                              hipStream_t stream)
{
    const float* query   = (const float*)d_in[0];
    const float* key     = (const float*)d_in[1];
    const float* value   = (const float*)d_in[2];
    const float* context = (const float*)d_in[3];
    const float* ipw     = (const float*)d_in[4];
    const float* ipb     = (const float*)d_in[5];
    const float* cw      = (const float*)d_in[6];
    const float* cb      = (const float*)d_in[7];
    const float* ow      = (const float*)d_in[8];
    const float* ob      = (const float*)d_in[9];
    const float* bias_k  = (const float*)d_in[10];
    const float* bias_v  = (const float*)d_in[11];
    float* out = (float*)d_out;
    float* ws  = (float*)d_ws;

    hipLaunchKernelGGL(k_pre1,    dim3(1024), dim3(256),  0, stream, query, context, ipw, ipb, cw, cb, ws);
    hipLaunchKernelGGL(k_pre23,   dim3(256),  dim3(1024), 0, stream, cw, ws);
    hipLaunchKernelGGL(k_g,       dim3(512),  dim3(256),  0, stream, ipw, ws);
    hipLaunchKernelGGL(k_gsum,    dim3(256),  dim3(256),  0, stream, ws);
    hipLaunchKernelGGL(k_scores,  dim3(512),  dim3(512),  0, stream, key, bias_k, ws);
    hipLaunchKernelGGL(k_softmax, dim3(256),  dim3(256),  0, stream, ws);
    hipLaunchKernelGGL(k_u,       dim3(512),  dim3(256),  0, stream, value, ws);
    hipLaunchKernelGGL(k_ured,    dim3(256),  dim3(256),  0, stream, ws, out);
    hipLaunchKernelGGL(k_attnpre, dim3(1024), dim3(256),  0, stream, ipw, ipb, bias_v, ws);
    hipLaunchKernelGGL(k_out,     dim3(1024), dim3(256),  0, stream, ow, ob, ws, out);
}